// Round 3
// baseline (252.283 us; speedup 1.0000x reference)
//
#include <hip/hip_runtime.h>

typedef __bf16 bf16x8 __attribute__((ext_vector_type(8)));
typedef float f32x4 __attribute__((ext_vector_type(4)));
typedef unsigned short u16;

#define B_ 2
#define T_ 2048
#define C_ 1024
#define H_ 16
#define D_ 64
// 0.125 * log2(e): folded into Q so attn softmax runs in exp2 domain
#define QSCALE 0.18033688011112042f

__device__ __forceinline__ u16 f2bf(float f) {
    unsigned u = __builtin_bit_cast(unsigned, f);
    u += 0x7fffu + ((u >> 16) & 1u);
    return (u16)(u >> 16);
}

__device__ __forceinline__ f32x4 mfma16(bf16x8 a, bf16x8 b, f32x4 c) {
    return __builtin_amdgcn_mfma_f32_16x16x32_bf16(a, b, c, 0, 0, 0);
}

// async global->LDS, 16B per lane; LDS dest = wave-uniform base + lane*16
__device__ __forceinline__ void gll16(const u16* g, u16* l) {
    __builtin_amdgcn_global_load_lds((const __attribute__((address_space(1))) unsigned int*)g,
                                     (__attribute__((address_space(3))) unsigned int*)l,
                                     16, 0, 0);
}

// ---------------- cast fp32 -> bf16 ----------------
__global__ __launch_bounds__(256) void cast_kernel(const float* __restrict__ in,
                                                   u16* __restrict__ out, int n) {
    int i = (blockIdx.x * 256 + threadIdx.x) * 4;
    if (i < n) {
        float4 v = *(const float4*)(in + i);
        out[i + 0] = f2bf(v.x);
        out[i + 1] = f2bf(v.y);
        out[i + 2] = f2bf(v.z);
        out[i + 3] = f2bf(v.w);
    }
}

// ---------------- transpose + cast: in [K][N] fp32 -> out [N][K] bf16 ----------------
__global__ __launch_bounds__(256) void transpose_cast_kernel(const float* __restrict__ in,
                                                             u16* __restrict__ out,
                                                             int K, int N) {
    __shared__ float tile[64][65];
    int k0 = blockIdx.y * 64, n0 = blockIdx.x * 64;
    int t = threadIdx.x;
    int c = t & 63;
    int r0 = t >> 6;
    for (int i = 0; i < 16; ++i) {
        int r = r0 * 16 + i;
        tile[r][c] = in[(k0 + r) * N + n0 + c];
    }
    __syncthreads();
    for (int i = 0; i < 16; ++i) {
        int rn = r0 * 16 + i;
        out[(n0 + rn) * K + k0 + c] = f2bf(tile[c][rn]);
    }
}

// ---------------- GEMM: C[M,N] = A[M,K] * Bt[N,K]^T  (bf16 in, fp32 acc) ----------------
// MODE 1: QK epilogue -> Q[bh,t,d] (pre-scaled by QSCALE), K[bh,t,d]   (N=2048)
// MODE 2: proj epilogue -> Cout[m,n] = acc + bias[n] (fp32)
// MODE 3: V^T gemm epilogue: row=d_global (0..1023), col=token (0..4095) -> Vt[bh,d,t]
template <int MODE>
__global__ __launch_bounds__(256) void gemm_bt(const u16* __restrict__ A,
                                               const u16* __restrict__ Bt,
                                               float* __restrict__ Cout,
                                               u16* __restrict__ Qo, u16* __restrict__ Ko,
                                               u16* __restrict__ Vto,
                                               const float* __restrict__ bias,
                                               int M, int N, int K) {
    __shared__ __align__(16) u16 As[128 * 32];
    __shared__ __align__(16) u16 Bs[128 * 32];
    int m0 = blockIdx.y * 128, n0 = blockIdx.x * 128;
    int t = threadIdx.x;
    int wave = t >> 6, lane = t & 63, lr = lane & 15, quad = lane >> 4;
    int wm = (wave >> 1) * 64, wn = (wave & 1) * 64;

    int srow = lane >> 2;               // 0..15
    int sgl = (lane & 3) ^ (srow & 3);  // swizzled group to fetch

    f32x4 acc[4][4];
    for (int i = 0; i < 4; ++i)
        for (int j = 0; j < 4; ++j) acc[i][j] = (f32x4){0.f, 0.f, 0.f, 0.f};

    int swz = (quad ^ (lr & 3)) * 8;

    for (int kb = 0; kb < K; kb += 32) {
        __syncthreads();
        for (int i = 0; i < 2; ++i) {
            int c = wave * 2 + i;
            int row = c * 16 + srow;
            gll16(&A[(size_t)(m0 + row) * K + kb + sgl * 8], &As[c * 512]);
            gll16(&Bt[(size_t)(n0 + row) * K + kb + sgl * 8], &Bs[c * 512]);
        }
        __syncthreads();
        bf16x8 af[4], bfr[4];
        for (int mt = 0; mt < 4; ++mt)
            af[mt] = *(const bf16x8*)&As[(wm + mt * 16 + lr) * 32 + swz];
        for (int nt = 0; nt < 4; ++nt)
            bfr[nt] = *(const bf16x8*)&Bs[(wn + nt * 16 + lr) * 32 + swz];
        for (int mt = 0; mt < 4; ++mt)
            for (int nt = 0; nt < 4; ++nt) acc[mt][nt] = mfma16(af[mt], bfr[nt], acc[mt][nt]);
    }

    for (int mt = 0; mt < 4; ++mt) {
        for (int nt = 0; nt < 4; ++nt) {
            for (int r = 0; r < 4; ++r) {
                int row = m0 + wm + mt * 16 + quad * 4 + r;
                int col = n0 + wn + nt * 16 + lr;
                float v = acc[mt][nt][r];
                if (MODE == 1) {
                    int part = col >> 10;  // 0:q 1:k
                    int rem = col & 1023;
                    int h = rem >> 6, d = rem & 63;
                    int b = row >> 11, tt = row & 2047;
                    int bh = b * H_ + h;
                    if (part == 0) Qo[((size_t)(bh * T_ + tt)) * D_ + d] = f2bf(v * QSCALE);
                    else           Ko[((size_t)(bh * T_ + tt)) * D_ + d] = f2bf(v);
                } else if (MODE == 3) {
                    int b = col >> 11, tt = col & 2047;
                    int h = row >> 6, d = row & 63;
                    Vto[(((size_t)(b * H_ + h)) * D_ + d) * T_ + tt] = f2bf(v);
                } else {
                    Cout[(size_t)row * N + col] = v + bias[col];
                }
            }
        }
    }
}

// ---------------- flash attention (causal) ----------------
// grid 512 (32 bh x 16 q-tiles of 128 rows); block 256 = 4 waves.
// Each wave: two independent 16-row q-tiles (rows wbase..+15, wbase+16..+31) for ILP;
// K/V fragments shared between the two tiles. exp2-domain softmax (Q pre-scaled).
__global__ __launch_bounds__(256) void attn_kernel(const u16* __restrict__ Q,
                                                   const u16* __restrict__ Kb,
                                                   const u16* __restrict__ Vt,
                                                   u16* __restrict__ Y) {
    __shared__ __align__(16) u16 Kls[2][64 * 64];
    __shared__ __align__(16) u16 Vls[2][64 * 64];
    __shared__ __align__(16) u16 Pls[4][2][16 * 64];
    int qt = 15 - (blockIdx.x >> 5);  // heavy-first
    int bh = blockIdx.x & 31;
    int t = threadIdx.x, wave = t >> 6, lane = t & 63, lr = lane & 15, quad = lane >> 4;
    int qbase = qt * 128 + wave * 32;

    const u16* qb = Q + ((size_t)bh * T_ + qbase + lr) * D_;
    bf16x8 qfA0 = *(const bf16x8*)(qb + quad * 8);
    bf16x8 qfA1 = *(const bf16x8*)(qb + 32 + quad * 8);
    bf16x8 qfB0 = *(const bf16x8*)(qb + 16 * D_ + quad * 8);
    bf16x8 qfB1 = *(const bf16x8*)(qb + 16 * D_ + 32 + quad * 8);

    int srow = lane >> 3;
    int sgl = (lane & 7) ^ srow;
    const u16* kbase = Kb + (size_t)bh * T_ * D_;
    const u16* vbase = Vt + (size_t)bh * D_ * T_;

    float mA[4], lA[4], mB[4], lB[4];
    f32x4 oA[4], oB[4];
    for (int r = 0; r < 4; ++r) { mA[r] = -INFINITY; lA[r] = 0.f; mB[r] = -INFINITY; lB[r] = 0.f; }
    for (int dt = 0; dt < 4; ++dt) { oA[dt] = (f32x4){0.f, 0.f, 0.f, 0.f}; oB[dt] = (f32x4){0.f, 0.f, 0.f, 0.f}; }

    u16* plA = &Pls[wave][0][0];
    u16* plB = &Pls[wave][1][0];
    int swz1 = (quad ^ (lr & 7)) * 8;
    int swz2 = ((quad + 4) ^ (lr & 7)) * 8;

    int ktw = 2 * qt + (wave >> 1);   // this wave's last (diagonal) tile
    int KTB = 2 * qt + 1;             // block-wide last tile

    auto softmax_tile = [&](f32x4* s, float* m, float* l, f32x4* o, u16* pl) {
        float alpha[4];
        for (int r = 0; r < 4; ++r) {
            float v = fmaxf(fmaxf(s[0][r], s[1][r]), fmaxf(s[2][r], s[3][r]));
            for (int off = 8; off >= 1; off >>= 1) v = fmaxf(v, __shfl_xor(v, off, 16));
            float nm = fmaxf(m[r], v);
            alpha[r] = __builtin_amdgcn_exp2f(m[r] - nm);
            m[r] = nm;
            float rs = 0.f;
            for (int st = 0; st < 4; ++st) {
                float p = __builtin_amdgcn_exp2f(s[st][r] - nm);
                s[st][r] = p;
                rs += p;
            }
            for (int off = 8; off >= 1; off >>= 1) rs += __shfl_xor(rs, off, 16);
            l[r] = l[r] * alpha[r] + rs;
        }
        for (int dt = 0; dt < 4; ++dt)
            for (int r = 0; r < 4; ++r) o[dt][r] *= alpha[r];
        for (int st = 0; st < 4; ++st)
            for (int r = 0; r < 4; ++r) {
                int rw = quad * 4 + r;
                int gl = st * 2 + (lr >> 3);
                pl[rw * 64 + ((gl ^ (rw & 7)) * 8) + (lr & 7)] = f2bf(s[st][r]);
            }
    };

    // prologue: stage kt=0 into buf 0
    for (int i = 0; i < 2; ++i) {
        int c = wave * 2 + i;
        int row = c * 8 + srow;
        gll16(kbase + (size_t)row * D_ + sgl * 8, &Kls[0][c * 512]);
        gll16(vbase + (size_t)row * T_ + sgl * 8, &Vls[0][c * 512]);
    }

    for (int kt = 0; kt <= KTB; ++kt) {
        int buf = kt & 1;
        __syncthreads();  // staging of buf complete; buf^1 free
        if (kt < KTB) {
            int nk = kt + 1;
            for (int i = 0; i < 2; ++i) {
                int c = wave * 2 + i;
                int row = c * 8 + srow;
                gll16(kbase + (size_t)(nk * 64 + row) * D_ + sgl * 8, &Kls[buf ^ 1][c * 512]);
                gll16(vbase + (size_t)row * T_ + nk * 64 + sgl * 8, &Vls[buf ^ 1][c * 512]);
            }
        }
        if (kt <= ktw) {
            bf16x8 kf0[4], kf1[4];
            for (int st = 0; st < 4; ++st) {
                const u16* kp = &Kls[buf][(st * 16 + lr) * 64];
                kf0[st] = *(const bf16x8*)(kp + swz1);
                kf1[st] = *(const bf16x8*)(kp + swz2);
            }
            f32x4 sA[4], sB[4];
            for (int st = 0; st < 4; ++st) { sA[st] = (f32x4){0.f, 0.f, 0.f, 0.f}; sB[st] = (f32x4){0.f, 0.f, 0.f, 0.f}; }
            for (int st = 0; st < 4; ++st) {
                sA[st] = mfma16(qfA0, kf0[st], sA[st]);
                sA[st] = mfma16(qfA1, kf1[st], sA[st]);
                sB[st] = mfma16(qfB0, kf0[st], sB[st]);
                sB[st] = mfma16(qfB1, kf1[st], sB[st]);
            }
            if (kt == ktw) {  // diagonal tile: causal mask
                for (int st = 0; st < 4; ++st) {
                    int colk = kt * 64 + st * 16 + lr;
                    for (int r = 0; r < 4; ++r) {
                        int rowA = qbase + quad * 4 + r;
                        if (colk > rowA) sA[st][r] = -INFINITY;
                        if (colk > rowA + 16) sB[st][r] = -INFINITY;
                    }
                }
            }
            softmax_tile(sA, mA, lA, oA, plA);
            bf16x8 apA0 = *(const bf16x8*)&plA[lr * 64 + swz1];
            bf16x8 apA1 = *(const bf16x8*)&plA[lr * 64 + swz2];
            softmax_tile(sB, mB, lB, oB, plB);
            bf16x8 apB0 = *(const bf16x8*)&plB[lr * 64 + swz1];
            bf16x8 apB1 = *(const bf16x8*)&plB[lr * 64 + swz2];
            for (int dt = 0; dt < 4; ++dt) {
                const u16* vp = &Vls[buf][(dt * 16 + lr) * 64];
                bf16x8 vf0 = *(const bf16x8*)(vp + swz1);
                bf16x8 vf1 = *(const bf16x8*)(vp + swz2);
                oA[dt] = mfma16(apA0, vf0, oA[dt]);
                oA[dt] = mfma16(apA1, vf1, oA[dt]);
                oB[dt] = mfma16(apB0, vf0, oB[dt]);
                oB[dt] = mfma16(apB1, vf1, oB[dt]);
            }
        }
    }

    // epilogue: Y[b, t, h*64 + d] bf16, both tiles
    int b = bh >> 4, h = bh & 15;
    for (int r = 0; r < 4; ++r) {
        int tgA = qbase + quad * 4 + r;
        float invA = 1.0f / lA[r];
        float invB = 1.0f / lB[r];
        for (int dt = 0; dt < 4; ++dt) {
            Y[((size_t)(b * T_ + tgA)) * C_ + h * 64 + dt * 16 + lr] = f2bf(oA[dt][r] * invA);
            Y[((size_t)(b * T_ + tgA + 16)) * C_ + h * 64 + dt * 16 + lr] = f2bf(oB[dt][r] * invB);
        }
    }
}

extern "C" void kernel_launch(void* const* d_in, const int* in_sizes, int n_in,
                              void* d_out, int out_size, void* d_ws, size_t ws_size,
                              hipStream_t stream) {
    const float* x      = (const float*)d_in[0];
    const float* w_qkv  = (const float*)d_in[1];
    const float* w_proj = (const float*)d_in[2];
    const float* b_proj = (const float*)d_in[3];
    float* out = (float*)d_out;

    char* ws = (char*)d_ws;
    u16* x_bf    = (u16*)(ws + 0);          // 8 MB
    u16* wqkv_t  = (u16*)(ws + 8388608);    // 6 MB [n=3072][k=1024]
    u16* wproj_t = (u16*)(ws + 14680064);   // 2 MB
    u16* q_bf    = (u16*)(ws + 16777216);   // 8 MB  [bh][t][d] (pre-scaled)
    u16* k_bf    = (u16*)(ws + 25165824);   // 8 MB  [bh][t][d]
    u16* vt_bf   = (u16*)(ws + 33554432);   // 8 MB  [bh][d][t]
    u16* y_bf    = (u16*)(ws + 41943040);   // 8 MB  [b*t][c]

    const int M = B_ * T_;  // 4096

    cast_kernel<<<M * C_ / 1024, 256, 0, stream>>>(x, x_bf, M * C_);
    transpose_cast_kernel<<<dim3(3 * C_ / 64, C_ / 64), 256, 0, stream>>>(w_qkv, wqkv_t, C_, 3 * C_);
    transpose_cast_kernel<<<dim3(C_ / 64, C_ / 64), 256, 0, stream>>>(w_proj, wproj_t, C_, C_);

    // QK gemm: [4096,1024] x [2048,1024]^T -> scatter Q,K
    gemm_bt<1><<<dim3(2 * C_ / 128, M / 128), 256, 0, stream>>>(
        x_bf, wqkv_t, nullptr, q_bf, k_bf, nullptr, nullptr, M, 2 * C_, C_);

    // V^T gemm: A = Wv^T [1024,1024], Bt = x [4096,1024] -> Vt[bh,d,t] row-major coalesced
    gemm_bt<3><<<dim3(M / 128, C_ / 128), 256, 0, stream>>>(
        wqkv_t + 2048 * 1024, x_bf, nullptr, nullptr, nullptr, vt_bf, nullptr, C_, M, C_);

    attn_kernel<<<32 * (T_ / 128), 256, 0, stream>>>(q_bf, k_bf, vt_bf, y_bf);

    gemm_bt<2><<<dim3(C_ / 128, M / 128), 256, 0, stream>>>(
        y_bf, wproj_t, out, nullptr, nullptr, nullptr, b_proj, M, C_, C_);
}

// Round 5
// 241.940 us; speedup vs baseline: 1.0428x; 1.0428x over previous
//
#include <hip/hip_runtime.h>

typedef __bf16 bf16x8 __attribute__((ext_vector_type(8)));
typedef float f32x4 __attribute__((ext_vector_type(4)));
typedef unsigned short u16;
typedef unsigned int u32;
typedef u32 u32x4 __attribute__((ext_vector_type(4)));

#define B_ 2
#define T_ 2048
#define C_ 1024
#define H_ 16
#define D_ 64
// 0.125 * log2(e): folded into Q so attn softmax runs in exp2 domain
#define QSCALE 0.18033688011112042f

__device__ __forceinline__ u16 f2bf(float f) {
    u32 u = __builtin_bit_cast(u32, f);
    u += 0x7fffu + ((u >> 16) & 1u);
    return (u16)(u >> 16);
}

__device__ __forceinline__ f32x4 mfma16(bf16x8 a, bf16x8 b, f32x4 c) {
    return __builtin_amdgcn_mfma_f32_16x16x32_bf16(a, b, c, 0, 0, 0);
}

// async global->LDS, 16B per lane; LDS dest = wave-uniform base + lane*16
__device__ __forceinline__ void gll16(const u16* g, u16* l) {
    __builtin_amdgcn_global_load_lds((const __attribute__((address_space(1))) unsigned int*)g,
                                     (__attribute__((address_space(3))) unsigned int*)l,
                                     16, 0, 0);
}

// ---------------- cast fp32 -> bf16 ----------------
__global__ __launch_bounds__(256) void cast_kernel(const float* __restrict__ in,
                                                   u16* __restrict__ out, int n) {
    int i = (blockIdx.x * 256 + threadIdx.x) * 4;
    if (i < n) {
        float4 v = *(const float4*)(in + i);
        out[i + 0] = f2bf(v.x);
        out[i + 1] = f2bf(v.y);
        out[i + 2] = f2bf(v.z);
        out[i + 3] = f2bf(v.w);
    }
}

// ---------------- transpose + cast: in [K][N] fp32 -> out [N][K] bf16 ----------------
__global__ __launch_bounds__(256) void transpose_cast_kernel(const float* __restrict__ in,
                                                             u16* __restrict__ out,
                                                             int K, int N) {
    __shared__ float tile[64][65];
    int k0 = blockIdx.y * 64, n0 = blockIdx.x * 64;
    int t = threadIdx.x;
    int c = t & 63;
    int r0 = t >> 6;
    for (int i = 0; i < 16; ++i) {
        int r = r0 * 16 + i;
        tile[r][c] = in[(k0 + r) * N + n0 + c];
    }
    __syncthreads();
    for (int i = 0; i < 16; ++i) {
        int rn = r0 * 16 + i;
        out[(n0 + rn) * K + k0 + c] = f2bf(tile[c][rn]);
    }
}

// ---------------- GEMM (round-3 verified, verbatim): C = A * Bt^T, tile 128x128 ----------------
// MODE 1: QK epilogue -> Q[bh,t,d] (pre-scaled by QSCALE), K[bh,t,d]   (N=2048)
// MODE 2: proj epilogue -> Cout[m,n] = acc + bias[n] (fp32)
// MODE 3: V^T gemm epilogue: row=d_global, col=token -> Vt[bh,d,t]
template <int MODE>
__global__ __launch_bounds__(256) void gemm_bt(const u16* __restrict__ A,
                                               const u16* __restrict__ Bt,
                                               float* __restrict__ Cout,
                                               u16* __restrict__ Qo, u16* __restrict__ Ko,
                                               u16* __restrict__ Vto,
                                               const float* __restrict__ bias,
                                               int M, int N, int K) {
    __shared__ __align__(16) u16 As[128 * 32];
    __shared__ __align__(16) u16 Bs[128 * 32];
    int m0 = blockIdx.y * 128, n0 = blockIdx.x * 128;
    int t = threadIdx.x;
    int wave = t >> 6, lane = t & 63, lr = lane & 15, quad = lane >> 4;
    int wm = (wave >> 1) * 64, wn = (wave & 1) * 64;

    int srow = lane >> 2;
    int sgl = (lane & 3) ^ (srow & 3);

    f32x4 acc[4][4];
    for (int i = 0; i < 4; ++i)
        for (int j = 0; j < 4; ++j) acc[i][j] = (f32x4){0.f, 0.f, 0.f, 0.f};

    int swz = (quad ^ (lr & 3)) * 8;

    for (int kb = 0; kb < K; kb += 32) {
        __syncthreads();
        for (int i = 0; i < 2; ++i) {
            int c = wave * 2 + i;
            int row = c * 16 + srow;
            gll16(&A[(size_t)(m0 + row) * K + kb + sgl * 8], &As[c * 512]);
            gll16(&Bt[(size_t)(n0 + row) * K + kb + sgl * 8], &Bs[c * 512]);
        }
        __syncthreads();
        bf16x8 af[4], bfr[4];
        for (int mt = 0; mt < 4; ++mt)
            af[mt] = *(const bf16x8*)&As[(wm + mt * 16 + lr) * 32 + swz];
        for (int nt = 0; nt < 4; ++nt)
            bfr[nt] = *(const bf16x8*)&Bs[(wn + nt * 16 + lr) * 32 + swz];
        for (int mt = 0; mt < 4; ++mt)
            for (int nt = 0; nt < 4; ++nt) acc[mt][nt] = mfma16(af[mt], bfr[nt], acc[mt][nt]);
    }

    for (int mt = 0; mt < 4; ++mt) {
        for (int nt = 0; nt < 4; ++nt) {
            for (int r = 0; r < 4; ++r) {
                int row = m0 + wm + mt * 16 + quad * 4 + r;
                int col = n0 + wn + nt * 16 + lr;
                float v = acc[mt][nt][r];
                if (MODE == 1) {
                    int part = col >> 10;  // 0:q 1:k
                    int rem = col & 1023;
                    int h = rem >> 6, d = rem & 63;
                    int b = row >> 11, tt = row & 2047;
                    int bh = b * H_ + h;
                    if (part == 0) Qo[((size_t)(bh * T_ + tt)) * D_ + d] = f2bf(v * QSCALE);
                    else           Ko[((size_t)(bh * T_ + tt)) * D_ + d] = f2bf(v);
                } else if (MODE == 3) {
                    int b = col >> 11, tt = col & 2047;
                    int h = row >> 6, d = row & 63;
                    Vto[(((size_t)(b * H_ + h)) * D_ + d) * T_ + tt] = f2bf(v);
                } else {
                    Cout[(size_t)row * N + col] = v + bias[col];
                }
            }
        }
    }
}

// ---------------- flash attention (causal), barrier-free, transposed ----------------
// grid 2048 x 64 threads: 1 wave per block, heavy-first. Wave owns 32 q-rows
// (2 subtiles of 16 sharing K/V fragments). S computed transposed (S^T = K Q^T)
// so softmax state is per-lane scalar (query = lane&15); reductions = 2 shuffles.
// O accumulated as O^T = V^T P^T. K frags register-double-buffered from global.
// P round-trips a 2KB per-wave LDS buffer; ALL P LDS traffic is u32-typed
// (store u32, load u32x4 -> bit_cast) + compiler fences: same-type accesses keep
// the machine scheduler from reordering across the in-order per-wave DS pipe.
__global__ __launch_bounds__(64, 2) void attn_kernel(const u16* __restrict__ Q,
                                                     const u16* __restrict__ Kb,
                                                     const u16* __restrict__ Vt,
                                                     u16* __restrict__ Y) {
    __shared__ __align__(16) u32 Pw[512];       // 16 queries x 64 keys, bf16-packed
    __shared__ __align__(16) float Els[16 * 65];
    int bx = blockIdx.x;
    int wtile = 63 - (bx >> 5);  // heavy-first
    int bh = bx & 31;
    int lane = threadIdx.x, lr = lane & 15, quad = lane >> 4;
    int KT = wtile >> 1;         // last (diagonal) 64-key tile
    int r0 = wtile * 32;

    const u16* Kg = Kb + (size_t)bh * (T_ * D_);
    const u16* Vg = Vt + (size_t)bh * (D_ * T_);
    const u16* Qg = Q + ((size_t)bh * T_ + r0 + lr) * D_;
    bf16x8 qAl = *(const bf16x8*)(Qg + quad * 8);
    bf16x8 qAh = *(const bf16x8*)(Qg + 32 + quad * 8);
    bf16x8 qBl = *(const bf16x8*)(Qg + 16 * D_ + quad * 8);
    bf16x8 qBh = *(const bf16x8*)(Qg + 16 * D_ + 32 + quad * 8);

    float mA = -__builtin_inff(), lA = 0.f, mB = -__builtin_inff(), lB = 0.f;
    f32x4 oA[4], oB[4];
#pragma unroll
    for (int dt = 0; dt < 4; ++dt) { oA[dt] = (f32x4){0.f, 0.f, 0.f, 0.f}; oB[dt] = (f32x4){0.f, 0.f, 0.f, 0.f}; }

    int pwbase = lr * 32 + (quad & 1) * 2;
    int rg1 = (quad ^ (lr & 7)) << 2;        // u32 group offset, logical keys quad*8..+7
    int rg2 = ((quad + 4) ^ (lr & 7)) << 2;  // u32 group offset, logical keys 32+quad*8..+7

    // softmax + P-pack + PV for one 16-query subtile (s holds S^T in C-layout:
    // key = st*16 + quad*4 + r, query = lr)
    auto smax_pv = [&](f32x4* s, float& m, float& l, f32x4* o,
                       const bf16x8* vl, const bf16x8* vh) {
        float t0 = fmaxf(fmaxf(s[0][0], s[0][1]), fmaxf(s[0][2], s[0][3]));
        float t1 = fmaxf(fmaxf(s[1][0], s[1][1]), fmaxf(s[1][2], s[1][3]));
        float t2 = fmaxf(fmaxf(s[2][0], s[2][1]), fmaxf(s[2][2], s[2][3]));
        float t3 = fmaxf(fmaxf(s[3][0], s[3][1]), fmaxf(s[3][2], s[3][3]));
        float vm = fmaxf(fmaxf(t0, t1), fmaxf(t2, t3));
        vm = fmaxf(vm, __shfl_xor(vm, 16));
        vm = fmaxf(vm, __shfl_xor(vm, 32));
        float nm = fmaxf(m, vm);
        float alpha = __builtin_amdgcn_exp2f(m - nm);
        m = nm;
        float sum = 0.f;
#pragma unroll
        for (int st = 0; st < 4; ++st)
#pragma unroll
            for (int r = 0; r < 4; ++r) {
                float p = __builtin_amdgcn_exp2f(s[st][r] - nm);
                s[st][r] = p;
                sum += p;
            }
        sum += __shfl_xor(sum, 16);
        sum += __shfl_xor(sum, 32);
        l = l * alpha + sum;
#pragma unroll
        for (int dt = 0; dt < 4; ++dt)
#pragma unroll
            for (int r = 0; r < 4; ++r) o[dt][r] *= alpha;
        // P[query][key] -> swizzled LDS, bf16 RNE pack, u32-typed stores
        asm volatile("" ::: "memory");
#pragma unroll
        for (int st = 0; st < 4; ++st)
#pragma unroll
            for (int rp = 0; rp < 2; ++rp) {
                u32 lo = f2bf(s[st][2 * rp]);
                u32 hi = f2bf(s[st][2 * rp + 1]);
                Pw[pwbase + (((st * 2 + (quad >> 1)) ^ (lr & 7)) << 2) + rp] = lo | (hi << 16);
            }
        asm volatile("" ::: "memory");
        const u32* prow = &Pw[lr * 32];
        u32x4 plo = *(const u32x4*)(prow + rg1);
        u32x4 phi = *(const u32x4*)(prow + rg2);
        asm volatile("" ::: "memory");
        bf16x8 pfl = __builtin_bit_cast(bf16x8, plo);
        bf16x8 pfh = __builtin_bit_cast(bf16x8, phi);
#pragma unroll
        for (int dt = 0; dt < 4; ++dt) {
            o[dt] = mfma16(vl[dt], pfl, o[dt]);
            o[dt] = mfma16(vh[dt], pfh, o[dt]);
        }
    };

    // one kt iteration; kc* = current K frags, kn* = where to prefetch next
    auto body = [&](int kt, bf16x8 (&kcl)[4], bf16x8 (&kch)[4],
                    bf16x8 (&knl)[4], bf16x8 (&knh)[4]) {
        if (kt < KT) {
            const u16* kn = Kg + (size_t)((kt + 1) * 64 + lr) * D_ + quad * 8;
#pragma unroll
            for (int st = 0; st < 4; ++st) {
                knl[st] = *(const bf16x8*)(kn + st * 16 * D_);
                knh[st] = *(const bf16x8*)(kn + st * 16 * D_ + 32);
            }
        }
        bf16x8 vl[4], vh[4];
        const u16* vp = Vg + (size_t)lr * T_ + kt * 64 + quad * 8;
#pragma unroll
        for (int dt = 0; dt < 4; ++dt) {
            vl[dt] = *(const bf16x8*)(vp + dt * 16 * T_);
            vh[dt] = *(const bf16x8*)(vp + dt * 16 * T_ + 32);
        }
        bool diag = (kt == KT);
        f32x4 s[4];
        // subtile A (queries r0..r0+15)
#pragma unroll
        for (int st = 0; st < 4; ++st) {
            s[st] = mfma16(kcl[st], qAl, (f32x4){0.f, 0.f, 0.f, 0.f});
            s[st] = mfma16(kch[st], qAh, s[st]);
        }
        if (diag) {
            int qrow = r0 + lr;
#pragma unroll
            for (int st = 0; st < 4; ++st)
#pragma unroll
                for (int r = 0; r < 4; ++r) {
                    int key = kt * 64 + st * 16 + quad * 4 + r;
                    if (key > qrow) s[st][r] = -__builtin_inff();
                }
        }
        smax_pv(s, mA, lA, oA, vl, vh);
        // subtile B (queries r0+16..r0+31)
#pragma unroll
        for (int st = 0; st < 4; ++st) {
            s[st] = mfma16(kcl[st], qBl, (f32x4){0.f, 0.f, 0.f, 0.f});
            s[st] = mfma16(kch[st], qBh, s[st]);
        }
        if (diag) {
            int qrow = r0 + 16 + lr;
#pragma unroll
            for (int st = 0; st < 4; ++st)
#pragma unroll
                for (int r = 0; r < 4; ++r) {
                    int key = kt * 64 + st * 16 + quad * 4 + r;
                    if (key > qrow) s[st][r] = -__builtin_inff();
                }
        }
        smax_pv(s, mB, lB, oB, vl, vh);
    };

    // prologue: K frags for kt=0
    bf16x8 k0l[4], k0h[4], k1l[4], k1h[4];
    {
        const u16* kp = Kg + (size_t)lr * D_ + quad * 8;
#pragma unroll
        for (int st = 0; st < 4; ++st) {
            k0l[st] = *(const bf16x8*)(kp + st * 16 * D_);
            k0h[st] = *(const bf16x8*)(kp + st * 16 * D_ + 32);
        }
    }
    int kt = 0;
    for (;;) {
        body(kt, k0l, k0h, k1l, k1h);
        if (kt == KT) break;
        ++kt;
        body(kt, k1l, k1h, k0l, k0h);
        if (kt == KT) break;
        ++kt;
    }

    // epilogue: O^T -> Y[b, t, h*64+d] via per-wave LDS transpose (float-typed both ways)
    int b = bh >> 4, h = bh & 15;
    int query = lane >> 2, dc = (lane & 3) * 16;
    auto epi = [&](float lv, f32x4* o, int rowoff) {
        float inv = 1.0f / lv;
        asm volatile("" ::: "memory");
#pragma unroll
        for (int dt = 0; dt < 4; ++dt)
#pragma unroll
            for (int r = 0; r < 4; ++r)
                Els[lr * 65 + dt * 16 + quad * 4 + r] = o[dt][r] * inv;
        asm volatile("" ::: "memory");
        u32 w[8];
#pragma unroll
        for (int j = 0; j < 8; ++j) {
            u32 lo = f2bf(Els[query * 65 + dc + 2 * j]);
            u32 hi = f2bf(Els[query * 65 + dc + 2 * j + 1]);
            w[j] = lo | (hi << 16);
        }
        asm volatile("" ::: "memory");
        u32* dst = (u32*)(Y + ((size_t)(b * T_ + r0 + rowoff + query)) * C_ + h * 64 + dc);
        *(u32x4*)dst = (u32x4){w[0], w[1], w[2], w[3]};
        *(u32x4*)(dst + 4) = (u32x4){w[4], w[5], w[6], w[7]};
    };
    epi(lA, oA, 0);
    epi(lB, oB, 16);
}

extern "C" void kernel_launch(void* const* d_in, const int* in_sizes, int n_in,
                              void* d_out, int out_size, void* d_ws, size_t ws_size,
                              hipStream_t stream) {
    const float* x      = (const float*)d_in[0];
    const float* w_qkv  = (const float*)d_in[1];
    const float* w_proj = (const float*)d_in[2];
    const float* b_proj = (const float*)d_in[3];
    float* out = (float*)d_out;

    char* ws = (char*)d_ws;
    u16* x_bf    = (u16*)(ws + 0);          // 8 MB
    u16* wqkv_t  = (u16*)(ws + 8388608);    // 6 MB [n=3072][k=1024]
    u16* wproj_t = (u16*)(ws + 14680064);   // 2 MB
    u16* q_bf    = (u16*)(ws + 16777216);   // 8 MB  [bh][t][d] (pre-scaled)
    u16* k_bf    = (u16*)(ws + 25165824);   // 8 MB  [bh][t][d]
    u16* vt_bf   = (u16*)(ws + 33554432);   // 8 MB  [bh][d][t]
    u16* y_bf    = (u16*)(ws + 41943040);   // 8 MB  [b*t][c]

    const int M = B_ * T_;  // 4096

    cast_kernel<<<M * C_ / 1024, 256, 0, stream>>>(x, x_bf, M * C_);
    transpose_cast_kernel<<<dim3(3 * C_ / 64, C_ / 64), 256, 0, stream>>>(w_qkv, wqkv_t, C_, 3 * C_);
    transpose_cast_kernel<<<dim3(C_ / 64, C_ / 64), 256, 0, stream>>>(w_proj, wproj_t, C_, C_);

    // QK gemm: [4096,1024] x [2048,1024]^T -> Q,K
    gemm_bt<1><<<dim3(2 * C_ / 128, M / 128), 256, 0, stream>>>(
        x_bf, wqkv_t, nullptr, q_bf, k_bf, nullptr, nullptr, M, 2 * C_, C_);

    // V^T gemm: A = Wv^T [1024,1024], Bt = x [4096,1024] -> Vt[bh,d,t]
    gemm_bt<3><<<dim3(M / 128, C_ / 128), 256, 0, stream>>>(
        wqkv_t + 2048 * 1024, x_bf, nullptr, nullptr, nullptr, vt_bf, nullptr, C_, M, C_);

    // barrier-free flash attention: 2048 one-wave blocks
    attn_kernel<<<32 * (T_ / 32), 64, 0, stream>>>(q_bf, k_bf, vt_bf, y_bf);

    // proj gemm: [4096,1024] x [1024,1024]^T + bias
    gemm_bt<2><<<dim3(C_ / 128, M / 128), 256, 0, stream>>>(
        y_bf, wproj_t, out, nullptr, nullptr, nullptr, b_proj, M, C_, C_);
}